// Round 10
// baseline (219.809 us; speedup 1.0000x reference)
//
#include <hip/hip_runtime.h>
#include <math.h>

#define N_NODES 20000
#define N_EDGES 320000
#define TOT_E   340000      // E + N self loops
#define IN_F    512
#define HC      512         // H*C
#define NHEAD   4
#define CHAN    128
#define NEG_SLOPE 0.2f
#define BN_EPS  1e-5f

#define GEMM_BM 32
#define LDS_STRIDE 72       // bf16 elems per LDS row: 64 + 8 pad (144B)

#define PACK_BLOCKS 128     // B-pack blocks
#define PREP_BLOCKS 256

#define GATHER_CHUNK 16     // nodes per gather block (4 waves x 4)

typedef short short8v __attribute__((ext_vector_type(8)));   // 8 bf16 (4 VGPRs)
typedef float f32x4  __attribute__((ext_vector_type(4)));
typedef unsigned short u16x8 __attribute__((ext_vector_type(8)));
typedef unsigned short u16x4 __attribute__((ext_vector_type(4)));

// ---- f32 -> bf16 bits, round-to-nearest-even ----
__device__ __forceinline__ unsigned short f2bf(float f) {
  unsigned u = __float_as_uint(f);
  return (unsigned short)((u + 0x7FFFu + ((u >> 16) & 1u)) >> 16);
}
__device__ __forceinline__ float bf2f(unsigned short b) {
  return __uint_as_float(((unsigned)b) << 16);
}

// ---- fused: pack B fragments (blocks 0..127) + prep (histogram, edge-attr
//      colsums, qmat) on the trailing PREP_BLOCKS blocks ----
__global__ void prep_pack_kernel(const float* __restrict__ W,
                                 unsigned short* __restrict__ Bp,
                                 const float* __restrict__ EA, const int* __restrict__ EI,
                                 const float* __restrict__ We, const float* __restrict__ aedg,
                                 float* __restrict__ msum, int* __restrict__ deg,
                                 float* __restrict__ qm) {
  if (blockIdx.x < PACK_BLOCKS) {
    // pack B: Bp[((n16*16 + k32)*64 + l)*8 + j] = W[k32*32+(l>>4)*8+j][n16*16+(l&15)]
    const int tid = blockIdx.x * blockDim.x + threadIdx.x;   // 32768
    const int l = tid & 63;
    const int k32 = (tid >> 6) & 15;
    const int n16 = tid >> 10;
    const int col = n16 * 16 + (l & 15);
    const int k = k32 * 32 + ((l >> 4) << 3);
    unsigned short v[8];
#pragma unroll
    for (int j = 0; j < 8; ++j) v[j] = f2bf(W[(size_t)(k + j) * HC + col]);
    *(short8v*)&Bp[(size_t)tid * 8] = *(short8v*)v;
  } else {
    const int bid = blockIdx.x - PACK_BLOCKS;    // 0..255
    // qmat: q[d][h] = sum_c W_edge[d, h*C+c] * att_edge[h, c]
    if (bid < 16 && threadIdx.x < 64) {
      const int d = bid >> 2, h = bid & 3, lane = threadIdx.x;
      const int base = h * CHAN + lane * 2;
      float v = We[d * HC + base] * aedg[base] + We[d * HC + base + 1] * aedg[base + 1];
#pragma unroll
      for (int m = 32; m >= 1; m >>= 1) v += __shfl_down(v, m);
      if (lane == 0) qm[d * 4 + h] = v;
    }
    float s0 = 0.f, s1 = 0.f, s2 = 0.f, s3 = 0.f;
    for (int i = bid * blockDim.x + threadIdx.x; i < N_EDGES;
         i += PREP_BLOCKS * blockDim.x) {
      const float4 v = *(const float4*)&EA[(size_t)i * 4];
      s0 += v.x; s1 += v.y; s2 += v.z; s3 += v.w;
      atomicAdd(&deg[EI[N_EDGES + i]], 1);
    }
#pragma unroll
    for (int m = 32; m >= 1; m >>= 1) {
      s0 += __shfl_down(s0, m); s1 += __shfl_down(s1, m);
      s2 += __shfl_down(s2, m); s3 += __shfl_down(s3, m);
    }
    __shared__ float red[4][4];
    const int lane = threadIdx.x & 63, wid = threadIdx.x >> 6;
    if (lane == 0) { red[wid][0] = s0; red[wid][1] = s1; red[wid][2] = s2; red[wid][3] = s3; }
    __syncthreads();
    if (threadIdx.x < 4) {
      float v = red[0][threadIdx.x] + red[1][threadIdx.x] + red[2][threadIdx.x] + red[3][threadIdx.x];
      atomicAdd(&msum[threadIdx.x], v);
    }
  }
}

// ---- exclusive prefix sum over deg[20000] -> rowstart[20001]; one block/1024thr ----
__global__ __launch_bounds__(1024) void scan_kernel(const int* __restrict__ deg,
                                                    int* __restrict__ rowstart) {
  __shared__ int part[1024];
  const int t = threadIdx.x;
  const int base = t * 20;
  int local[20];
  int s = 0;
#pragma unroll
  for (int i = 0; i < 20; ++i) {
    const int idx = base + i;
    const int v = (idx < N_NODES) ? deg[idx] : 0;
    local[i] = s;           // exclusive within chunk
    s += v;
  }
  part[t] = s;
  __syncthreads();
  for (int off = 1; off < 1024; off <<= 1) {
    const int v = (t >= off) ? part[t - off] : 0;
    __syncthreads();
    part[t] += v;
    __syncthreads();
  }
  const int excl = (t > 0) ? part[t - 1] : 0;
#pragma unroll
  for (int i = 0; i < 20; ++i) {
    const int idx = base + i;
    if (idx < N_NODES) rowstart[idx] = excl + local[i];
  }
  if (t == 1023) rowstart[N_NODES] = part[1023];
}

// ---- h = x @ W via bf16 MFMA, x read DIRECTLY (f32->bf16 LDS staging) ----
// BM=32 rows/block, full 512 cols; wave w == head w (cols w*128..+128).
// Fused per-head att dots (pure shfl reduce, no LDS).
__global__ __launch_bounds__(256) void gemm_direct_fused(
    const float* __restrict__ X, const unsigned short* __restrict__ Bp_,
    const float* __restrict__ att_s, const float* __restrict__ att_d,
    unsigned short* __restrict__ H16, float* __restrict__ a_src,
    float* __restrict__ a_dst) {
  __shared__ unsigned short As[GEMM_BM * LDS_STRIDE];   // 4608 B
  const short8v* __restrict__ Bp = (const short8v*)Bp_;
  const int tid = threadIdx.x;
  const int l = tid & 63;
  const int w = tid >> 6;                  // wave index == head == col quarter
  const int bm = blockIdx.x * GEMM_BM;     // 625 blocks * 32 = 20000 exact
  // staging: thread t loads 8 f32 of row (t>>3), k-chunk (t&7)*8
  const int srow = tid >> 3;
  const int skc = (tid & 7) * 8;
  const int grow = bm + srow;
  // fragment read indices
  const int fr = l & 15;                   // row-in-frag
  const int fg = l >> 4;                   // 8-elem k-chunk 0..3
  const int cl = l & 15;
  f32x4 acc[2][8] = {};
  for (int k0 = 0; k0 < IN_F; k0 += 64) {
    float4 f0 = {0.f, 0.f, 0.f, 0.f}, f1 = {0.f, 0.f, 0.f, 0.f};
    if (grow < N_NODES) {
      f0 = *(const float4*)&X[(size_t)grow * IN_F + k0 + skc];
      f1 = *(const float4*)&X[(size_t)grow * IN_F + k0 + skc + 4];
    }
    unsigned short vv[8] = {f2bf(f0.x), f2bf(f0.y), f2bf(f0.z), f2bf(f0.w),
                            f2bf(f1.x), f2bf(f1.y), f2bf(f1.z), f2bf(f1.w)};
    __syncthreads();                        // previous-iter reads done
    *(short8v*)&As[srow * LDS_STRIDE + skc] = *(short8v*)vv;
    __syncthreads();
#pragma unroll
    for (int ks = 0; ks < 2; ++ks) {
      const int kk = (k0 >> 5) + ks;        // global 32-k index for B
      short8v a[2], b[8];
#pragma unroll
      for (int m = 0; m < 2; ++m)
        a[m] = *(const short8v*)&As[(m * 16 + fr) * LDS_STRIDE + ks * 32 + fg * 8];
#pragma unroll
      for (int n = 0; n < 8; ++n)
        b[n] = Bp[((size_t)(w * 8 + n) * 16 + kk) * 64 + l];
#pragma unroll
      for (int m = 0; m < 2; ++m)
#pragma unroll
        for (int n = 0; n < 8; ++n)
          acc[m][n] = __builtin_amdgcn_mfma_f32_16x16x32_bf16(a[m], b[n], acc[m][n], 0, 0, 0);
    }
  }
  // ---- store h in bf16 (C/D: col = l&15, row = (l>>4)*4 + r) ----
  const int rbase = fg * 4;
#pragma unroll
  for (int m = 0; m < 2; ++m) {
#pragma unroll
    for (int r = 0; r < 4; ++r) {
      const int row = bm + m * 16 + rbase + r;
#pragma unroll
      for (int n = 0; n < 8; ++n)
        H16[(size_t)row * HC + (w * 8 + n) * 16 + cl] = f2bf(acc[m][n][r]);
    }
  }
  // ---- fused att dots: wave w holds ALL 128 cols of head w ----
  float as_v[8], ad_v[8];
#pragma unroll
  for (int n = 0; n < 8; ++n) {
    const int c = w * CHAN + n * 16 + cl;
    as_v[n] = att_s[c];
    ad_v[n] = att_d[c];
  }
#pragma unroll
  for (int m = 0; m < 2; ++m) {
#pragma unroll
    for (int r = 0; r < 4; ++r) {
      float ps = 0.f, pd = 0.f;
#pragma unroll
      for (int n = 0; n < 8; ++n) { ps += acc[m][n][r] * as_v[n]; pd += acc[m][n][r] * ad_v[n]; }
#pragma unroll
      for (int mask = 1; mask <= 8; mask <<= 1) {
        ps += __shfl_xor(ps, mask); pd += __shfl_xor(pd, mask);
      }
      if (cl == 0) {
        const int row = bm + m * 16 + rbase + r;
        a_src[row * 4 + w] = ps;
        a_dst[row * 4 + w] = pd;
      }
    }
  }
}

// ---- fused scatter + alpha: CSR position + leaky-relu'd alpha written in CSR order ----
__global__ void scatter_alpha_kernel(const int* __restrict__ EI, const float* __restrict__ EA,
                                     const int* __restrict__ rowstart, int* __restrict__ cnt,
                                     const float* __restrict__ a_src, const float* __restrict__ a_dst,
                                     const float* __restrict__ msum, const float* __restrict__ q,
                                     int* __restrict__ csr_src, float* __restrict__ alphacsr) {
  const int k = blockIdx.x * blockDim.x + threadIdx.x;
  if (k >= TOT_E) return;
  int s, d, pos;
  float e0, e1, e2, e3;
  if (k < N_EDGES) {
    s = EI[k]; d = EI[N_EDGES + k];
    const float4 e = *(const float4*)&EA[(size_t)k * 4];
    e0 = e.x; e1 = e.y; e2 = e.z; e3 = e.w;
    pos = rowstart[d] + atomicAdd(&cnt[d], 1);
    csr_src[pos] = s;
  } else {
    s = d = k - N_EDGES;
    const float inv = 1.0f / (float)N_EDGES;
    e0 = msum[0] * inv; e1 = msum[1] * inv; e2 = msum[2] * inv; e3 = msum[3] * inv;
    pos = k;                       // self region: identity
  }
  const float4 as = *(const float4*)&a_src[s * 4];
  const float4 ad = *(const float4*)&a_dst[d * 4];
  const float asv[4] = {as.x, as.y, as.z, as.w};
  const float adv[4] = {ad.x, ad.y, ad.z, ad.w};
  float al[4];
#pragma unroll
  for (int h = 0; h < 4; ++h) {
    float ae = e0 * q[h] + e1 * q[4 + h] + e2 * q[8 + h] + e3 * q[12 + h];
    float a = asv[h] + adv[h] + ae;
    al[h] = (a >= 0.f) ? a : NEG_SLOPE * a;
  }
  float4 o = {al[0], al[1], al[2], al[3]};
  *(float4*)&alphacsr[(size_t)pos * 4] = o;
}

// ---- per-node softmax: alphacsr -> head-major normalized weights w_h ----
// One wave per node; 16 lanes per head stride the CSR range.
__global__ __launch_bounds__(256) void softmax_w_kernel(
    const int* __restrict__ rowstart, const float* __restrict__ alphacsr,
    float* __restrict__ w_h) {
  const int wid = threadIdx.x >> 6;
  const int n = blockIdx.x * 4 + wid;           // 5000 blocks * 4 = 20000
  const int l = threadIdx.x & 63;
  const int head = l >> 4;
  const int lo = l & 15;
  const int beg = rowstart[n], end = rowstart[n + 1];
  const float aself = alphacsr[(size_t)(N_EDGES + n) * 4 + head];
  float m = aself;
  for (int p = beg + lo; p < end; p += 16)
    m = fmaxf(m, alphacsr[(size_t)p * 4 + head]);
#pragma unroll
  for (int mask = 1; mask <= 8; mask <<= 1) m = fmaxf(m, __shfl_xor(m, mask));
  float den = 0.f;
  for (int p = beg + lo; p < end; p += 16)
    den += __expf(alphacsr[(size_t)p * 4 + head] - m);
#pragma unroll
  for (int mask = 1; mask <= 8; mask <<= 1) den += __shfl_xor(den, mask);
  den += __expf(aself - m);
  const float dinv = 1.0f / (den + 1e-16f);
  float* __restrict__ wd = w_h + (size_t)head * TOT_E;
  for (int p = beg + lo; p < end; p += 16)
    wd[p] = __expf(alphacsr[(size_t)p * 4 + head] - m) * dinv;
  if (lo == 0) wd[N_EDGES + n] = __expf(aself - m) * dinv;
}

// ---- XCD-affine channel-sliced gather + BN partial stats ----
// slice = blockIdx&7 (64 channels, 2.56MB of H16 -> fits one XCD L2).
// Wave: 4 edge-groups x 16 channel-lanes; 4 H16 row loads in flight.
__global__ __launch_bounds__(256) void gather_sliced_kernel(
    const int* __restrict__ rowstart, const int* __restrict__ csr_src,
    const float* __restrict__ w_h, const unsigned short* __restrict__ H16,
    unsigned short* __restrict__ o16, float* __restrict__ psum,
    float* __restrict__ psq) {
  __shared__ float sv[4][64];
  const int slice = blockIdx.x & 7;            // -> XCD (round-robin dispatch)
  const int chunk = blockIdx.x >> 3;           // 0..1249
  const int wid = threadIdx.x >> 6;
  const int l = threadIdx.x & 63;
  const int eg = l >> 4;                       // edge group 0..3
  const int cl = l & 15;                       // channel lane
  const int ch = slice * 64 + cl * 4;          // this lane's 4 channels
  const float* __restrict__ wd = w_h + (size_t)(slice >> 1) * TOT_E;
  float ssum[4] = {0.f, 0.f, 0.f, 0.f}, ssq[4] = {0.f, 0.f, 0.f, 0.f};
#pragma unroll 1
  for (int g = 0; g < GATHER_CHUNK / 4; ++g) {
    const int n = chunk * GATHER_CHUNK + g * 4 + wid;
    const int beg = rowstart[n], end = rowstart[n + 1];
    float acc[4] = {0.f, 0.f, 0.f, 0.f};
    int idx = beg + eg;
    int src_cur = (idx < end) ? csr_src[idx] : -1;
    for (int p0 = beg; p0 < end; p0 += 4) {
      const int i2 = p0 + 4 + eg;
      const int src_nxt = (i2 < end) ? csr_src[i2] : -1;
      if (src_cur >= 0) {
        const float w = wd[p0 + eg];
        const u16x4 v = *(const u16x4*)&H16[(size_t)src_cur * HC + ch];
        acc[0] += w * bf2f(v[0]); acc[1] += w * bf2f(v[1]);
        acc[2] += w * bf2f(v[2]); acc[3] += w * bf2f(v[3]);
      }
      src_cur = src_nxt;
    }
#pragma unroll
    for (int c = 0; c < 4; ++c) {
      acc[c] += __shfl_xor(acc[c], 16);
      acc[c] += __shfl_xor(acc[c], 32);
    }
    if (eg == 0) {
      const float wself = wd[N_EDGES + n];
      const u16x4 hv = *(const u16x4*)&H16[(size_t)n * HC + ch];
      unsigned short ov[4];
#pragma unroll
      for (int c = 0; c < 4; ++c) {
        acc[c] += wself * bf2f(hv[c]);
        ov[c] = f2bf(acc[c]);
        ssum[c] += acc[c];
        ssq[c] += acc[c] * acc[c];
      }
      *(u16x4*)&o16[(size_t)n * HC + ch] = *(u16x4*)ov;
    }
  }
  // ---- BN partials: cross-wave LDS reduce, 128 atomics/block ----
  if (eg == 0) {
#pragma unroll
    for (int c = 0; c < 4; ++c) sv[wid][cl * 4 + c] = ssum[c];
  }
  __syncthreads();
  if (threadIdx.x < 64) {
    const float v = sv[0][threadIdx.x] + sv[1][threadIdx.x] +
                    sv[2][threadIdx.x] + sv[3][threadIdx.x];
    atomicAdd(&psum[slice * 64 + threadIdx.x], v);
  }
  __syncthreads();
  if (eg == 0) {
#pragma unroll
    for (int c = 0; c < 4; ++c) sv[wid][cl * 4 + c] = ssq[c];
  }
  __syncthreads();
  if (threadIdx.x < 64) {
    const float v = sv[0][threadIdx.x] + sv[1][threadIdx.x] +
                    sv[2][threadIdx.x] + sv[3][threadIdx.x];
    atomicAdd(&psq[slice * 64 + threadIdx.x], v);
  }
}

// ---- per-channel scale/shift (bias cancels exactly in BN) ----
__global__ void bn_reduce_kernel(const float* __restrict__ psum, const float* __restrict__ psq,
                                 const float* __restrict__ gamma, const float* __restrict__ beta,
                                 float* __restrict__ scale, float* __restrict__ shift) {
  const int c = threadIdx.x;     // 512
  const float mu = psum[c] * (1.0f / N_NODES);
  const float var = psq[c] * (1.0f / N_NODES) - mu * mu;
  const float sc = gamma[c] * rsqrtf(var + BN_EPS);
  scale[c] = sc;
  shift[c] = beta[c] - mu * sc;
}

// ---- BN normalize: read bf16 pre-BN rows, write final f32 out ----
__global__ void bn_apply_kernel(const unsigned short* __restrict__ o16,
                                const float* __restrict__ scale,
                                const float* __restrict__ shift,
                                float* __restrict__ out) {
  const int i = blockIdx.x * blockDim.x + threadIdx.x;   // float4 index
  if (i >= N_NODES * HC / 4) return;
  const int j4 = (i & (HC / 4 - 1)) * 4;
  const u16x4 v16 = *(const u16x4*)&o16[(size_t)i * 4];
  const float4 sc = *(const float4*)&scale[j4];
  const float4 sh = *(const float4*)&shift[j4];
  float4 v;
  v.x = bf2f(v16[0]) * sc.x + sh.x;
  v.y = bf2f(v16[1]) * sc.y + sh.y;
  v.z = bf2f(v16[2]) * sc.z + sh.z;
  v.w = bf2f(v16[3]) * sc.w + sh.w;
  ((float4*)out)[i] = v;
}

extern "C" void kernel_launch(void* const* d_in, const int* in_sizes, int n_in,
                              void* d_out, int out_size, void* d_ws, size_t ws_size,
                              hipStream_t stream) {
  const float* x     = (const float*)d_in[0];
  const int*   ei    = (const int*)d_in[1];
  const float* ea    = (const float*)d_in[2];
  const float* W     = (const float*)d_in[3];
  const float* We    = (const float*)d_in[4];
  const float* att_s = (const float*)d_in[5];
  const float* att_d = (const float*)d_in[6];
  const float* att_e = (const float*)d_in[7];
  // d_in[8] = bias: cancels exactly in BatchNorm -> unused
  const float* gamma = (const float*)d_in[9];
  const float* beta  = (const float*)d_in[10];
  float* out = (float*)d_out;
  float* ws  = (float*)d_ws;

  // workspace layout
  unsigned short* H16     = (unsigned short*)ws;                   // N*512 bf16
  float*    a_src   = (float*)(H16 + (size_t)N_NODES * HC);        // N*4
  float*    a_dst   = a_src + N_NODES * NHEAD;                     // N*4
  float*    alphacsr= a_dst + N_NODES * NHEAD;                     // TOT_E*4
  float*    w_h     = alphacsr + (size_t)TOT_E * NHEAD;            // 4*TOT_E head-major
  float*    qm      = w_h + (size_t)NHEAD * TOT_E;                 // 16
  float*    scale   = qm + 16;                                     // 512
  float*    shift   = scale + HC;                                  // 512
  int*      rowstart= (int*)(shift + HC);                          // N+1 (pad 20004)
  int*      csr_src = rowstart + 20004;                            // E
  unsigned short* Bp  = (unsigned short*)(csr_src + N_EDGES);      // 32*16*64*8 ush
  unsigned short* o16 = Bp + (size_t)32 * 16 * 64 * 8;             // N*512 bf16
  // ---- zeroed-every-call block ----
  int*      deg     = (int*)(o16 + (size_t)N_NODES * HC);          // N
  int*      cnt     = deg + N_NODES;                               // N
  float*    msum    = (float*)(cnt + N_NODES);                     // 4
  float*    psum    = msum + 4;                                    // 512
  float*    psq     = psum + HC;                                   // 512

  const size_t zero_bytes = (size_t)(N_NODES * 2 + 4 + HC * 2) * sizeof(float);
  hipMemsetAsync(deg, 0, zero_bytes, stream);

  prep_pack_kernel<<<PACK_BLOCKS + PREP_BLOCKS, 256, 0, stream>>>(
      W, Bp, ea, ei, We, att_e, msum, deg, qm);
  scan_kernel<<<1, 1024, 0, stream>>>(deg, rowstart);
  gemm_direct_fused<<<N_NODES / GEMM_BM, 256, 0, stream>>>(x, Bp, att_s, att_d,
                                                           H16, a_src, a_dst);
  scatter_alpha_kernel<<<(TOT_E + 255) / 256, 256, 0, stream>>>(ei, ea, rowstart, cnt,
                                                                a_src, a_dst, msum, qm,
                                                                csr_src, alphacsr);
  softmax_w_kernel<<<N_NODES / 4, 256, 0, stream>>>(rowstart, alphacsr, w_h);
  gather_sliced_kernel<<<8 * (N_NODES / GATHER_CHUNK), 256, 0, stream>>>(
      rowstart, csr_src, w_h, H16, o16, psum, psq);
  bn_reduce_kernel<<<1, HC, 0, stream>>>(psum, psq, gamma, beta, scale, shift);
  bn_apply_kernel<<<(N_NODES * HC / 4 + 255) / 256, 256, 0, stream>>>(o16, scale, shift, out);
}

// Round 11
// 198.795 us; speedup vs baseline: 1.1057x; 1.1057x over previous
//
#include <hip/hip_runtime.h>
#include <math.h>

#define N_NODES 20000
#define N_EDGES 320000
#define TOT_E   340000      // E + N self loops
#define IN_F    512
#define HC      512         // H*C
#define NHEAD   4
#define CHAN    128
#define NEG_SLOPE 0.2f
#define BN_EPS  1e-5f

#define GEMM_BM 32
#define LDS_STRIDE 72       // bf16 elems per LDS row: 64 + 8 pad (144B)

#define PACK_BLOCKS 128     // B-pack blocks
#define PREP_BLOCKS 256

typedef short short8v __attribute__((ext_vector_type(8)));   // 8 bf16 (4 VGPRs)
typedef float f32x4  __attribute__((ext_vector_type(4)));
typedef unsigned short u16x8 __attribute__((ext_vector_type(8)));
typedef unsigned short u16x4 __attribute__((ext_vector_type(4)));

// ---- f32 -> bf16 bits, round-to-nearest-even ----
__device__ __forceinline__ unsigned short f2bf(float f) {
  unsigned u = __float_as_uint(f);
  return (unsigned short)((u + 0x7FFFu + ((u >> 16) & 1u)) >> 16);
}
__device__ __forceinline__ float bf2f(unsigned short b) {
  return __uint_as_float(((unsigned)b) << 16);
}

// ---- fused: pack B fragments (blocks 0..127) + prep (histogram, edge-attr
//      colsums, qmat) on the trailing PREP_BLOCKS blocks ----
__global__ void prep_pack_kernel(const float* __restrict__ W,
                                 unsigned short* __restrict__ Bp,
                                 const float* __restrict__ EA, const int* __restrict__ EI,
                                 const float* __restrict__ We, const float* __restrict__ aedg,
                                 float* __restrict__ msum, int* __restrict__ deg,
                                 float* __restrict__ qm) {
  if (blockIdx.x < PACK_BLOCKS) {
    // pack B: Bp[((n16*16 + k32)*64 + l)*8 + j] = W[k32*32+(l>>4)*8+j][n16*16+(l&15)]
    const int tid = blockIdx.x * blockDim.x + threadIdx.x;   // 32768
    const int l = tid & 63;
    const int k32 = (tid >> 6) & 15;
    const int n16 = tid >> 10;
    const int col = n16 * 16 + (l & 15);
    const int k = k32 * 32 + ((l >> 4) << 3);
    unsigned short v[8];
#pragma unroll
    for (int j = 0; j < 8; ++j) v[j] = f2bf(W[(size_t)(k + j) * HC + col]);
    *(short8v*)&Bp[(size_t)tid * 8] = *(short8v*)v;
  } else {
    const int bid = blockIdx.x - PACK_BLOCKS;    // 0..255
    // qmat: q[d][h] = sum_c W_edge[d, h*C+c] * att_edge[h, c]
    if (bid < 16 && threadIdx.x < 64) {
      const int d = bid >> 2, h = bid & 3, lane = threadIdx.x;
      const int base = h * CHAN + lane * 2;
      float v = We[d * HC + base] * aedg[base] + We[d * HC + base + 1] * aedg[base + 1];
#pragma unroll
      for (int m = 32; m >= 1; m >>= 1) v += __shfl_down(v, m);
      if (lane == 0) qm[d * 4 + h] = v;
    }
    float s0 = 0.f, s1 = 0.f, s2 = 0.f, s3 = 0.f;
    for (int i = bid * blockDim.x + threadIdx.x; i < N_EDGES;
         i += PREP_BLOCKS * blockDim.x) {
      const float4 v = *(const float4*)&EA[(size_t)i * 4];
      s0 += v.x; s1 += v.y; s2 += v.z; s3 += v.w;
      atomicAdd(&deg[EI[N_EDGES + i]], 1);
    }
#pragma unroll
    for (int m = 32; m >= 1; m >>= 1) {
      s0 += __shfl_down(s0, m); s1 += __shfl_down(s1, m);
      s2 += __shfl_down(s2, m); s3 += __shfl_down(s3, m);
    }
    __shared__ float red[4][4];
    const int lane = threadIdx.x & 63, wid = threadIdx.x >> 6;
    if (lane == 0) { red[wid][0] = s0; red[wid][1] = s1; red[wid][2] = s2; red[wid][3] = s3; }
    __syncthreads();
    if (threadIdx.x < 4) {
      float v = red[0][threadIdx.x] + red[1][threadIdx.x] + red[2][threadIdx.x] + red[3][threadIdx.x];
      atomicAdd(&msum[threadIdx.x], v);
    }
  }
}

// ---- exclusive prefix sum over deg[20000] -> rowstart[20001]; one block/1024thr ----
__global__ __launch_bounds__(1024) void scan_kernel(const int* __restrict__ deg,
                                                    int* __restrict__ rowstart) {
  __shared__ int part[1024];
  const int t = threadIdx.x;
  const int base = t * 20;
  int local[20];
  int s = 0;
#pragma unroll
  for (int i = 0; i < 20; ++i) {
    const int idx = base + i;
    const int v = (idx < N_NODES) ? deg[idx] : 0;
    local[i] = s;           // exclusive within chunk
    s += v;
  }
  part[t] = s;
  __syncthreads();
  for (int off = 1; off < 1024; off <<= 1) {
    const int v = (t >= off) ? part[t - off] : 0;
    __syncthreads();
    part[t] += v;
    __syncthreads();
  }
  const int excl = (t > 0) ? part[t - 1] : 0;
#pragma unroll
  for (int i = 0; i < 20; ++i) {
    const int idx = base + i;
    if (idx < N_NODES) rowstart[idx] = excl + local[i];
  }
  if (t == 1023) rowstart[N_NODES] = part[1023];
}

// ---- h = x @ W via bf16 MFMA, x read DIRECTLY (f32->bf16 LDS staging) ----
// BM=32 rows/block, full 512 cols; wave w == head w (cols w*128..+128).
// Fused per-head att dots (pure shfl reduce, no LDS).
__global__ __launch_bounds__(256) void gemm_direct_fused(
    const float* __restrict__ X, const unsigned short* __restrict__ Bp_,
    const float* __restrict__ att_s, const float* __restrict__ att_d,
    unsigned short* __restrict__ H16, float* __restrict__ a_src,
    float* __restrict__ a_dst) {
  __shared__ unsigned short As[GEMM_BM * LDS_STRIDE];   // 4608 B
  const short8v* __restrict__ Bp = (const short8v*)Bp_;
  const int tid = threadIdx.x;
  const int l = tid & 63;
  const int w = tid >> 6;                  // wave index == head == col quarter
  const int bm = blockIdx.x * GEMM_BM;     // 625 blocks * 32 = 20000 exact
  // staging: thread t loads 8 f32 of row (t>>3), k-chunk (t&7)*8
  const int srow = tid >> 3;
  const int skc = (tid & 7) * 8;
  const int grow = bm + srow;
  // fragment read indices
  const int fr = l & 15;                   // row-in-frag
  const int fg = l >> 4;                   // 8-elem k-chunk 0..3
  const int cl = l & 15;
  f32x4 acc[2][8] = {};
  for (int k0 = 0; k0 < IN_F; k0 += 64) {
    float4 f0 = {0.f, 0.f, 0.f, 0.f}, f1 = {0.f, 0.f, 0.f, 0.f};
    if (grow < N_NODES) {
      f0 = *(const float4*)&X[(size_t)grow * IN_F + k0 + skc];
      f1 = *(const float4*)&X[(size_t)grow * IN_F + k0 + skc + 4];
    }
    unsigned short vv[8] = {f2bf(f0.x), f2bf(f0.y), f2bf(f0.z), f2bf(f0.w),
                            f2bf(f1.x), f2bf(f1.y), f2bf(f1.z), f2bf(f1.w)};
    __syncthreads();                        // previous-iter reads done
    *(short8v*)&As[srow * LDS_STRIDE + skc] = *(short8v*)vv;
    __syncthreads();
#pragma unroll
    for (int ks = 0; ks < 2; ++ks) {
      const int kk = (k0 >> 5) + ks;        // global 32-k index for B
      short8v a[2], b[8];
#pragma unroll
      for (int m = 0; m < 2; ++m)
        a[m] = *(const short8v*)&As[(m * 16 + fr) * LDS_STRIDE + ks * 32 + fg * 8];
#pragma unroll
      for (int n = 0; n < 8; ++n)
        b[n] = Bp[((size_t)(w * 8 + n) * 16 + kk) * 64 + l];
#pragma unroll
      for (int m = 0; m < 2; ++m)
#pragma unroll
        for (int n = 0; n < 8; ++n)
          acc[m][n] = __builtin_amdgcn_mfma_f32_16x16x32_bf16(a[m], b[n], acc[m][n], 0, 0, 0);
    }
  }
  // ---- store h in bf16 (C/D: col = l&15, row = (l>>4)*4 + r) ----
  const int rbase = fg * 4;
#pragma unroll
  for (int m = 0; m < 2; ++m) {
#pragma unroll
    for (int r = 0; r < 4; ++r) {
      const int row = bm + m * 16 + rbase + r;
#pragma unroll
      for (int n = 0; n < 8; ++n)
        H16[(size_t)row * HC + (w * 8 + n) * 16 + cl] = f2bf(acc[m][n][r]);
    }
  }
  // ---- fused att dots: wave w holds ALL 128 cols of head w ----
  float as_v[8], ad_v[8];
#pragma unroll
  for (int n = 0; n < 8; ++n) {
    const int c = w * CHAN + n * 16 + cl;
    as_v[n] = att_s[c];
    ad_v[n] = att_d[c];
  }
#pragma unroll
  for (int m = 0; m < 2; ++m) {
#pragma unroll
    for (int r = 0; r < 4; ++r) {
      float ps = 0.f, pd = 0.f;
#pragma unroll
      for (int n = 0; n < 8; ++n) { ps += acc[m][n][r] * as_v[n]; pd += acc[m][n][r] * ad_v[n]; }
#pragma unroll
      for (int mask = 1; mask <= 8; mask <<= 1) {
        ps += __shfl_xor(ps, mask); pd += __shfl_xor(pd, mask);
      }
      if (cl == 0) {
        const int row = bm + m * 16 + rbase + r;
        a_src[row * 4 + w] = ps;
        a_dst[row * 4 + w] = pd;
      }
    }
  }
}

// ---- fused scatter + alpha: CSR position + leaky-relu'd alpha written in CSR order ----
__global__ void scatter_alpha_kernel(const int* __restrict__ EI, const float* __restrict__ EA,
                                     const int* __restrict__ rowstart, int* __restrict__ cnt,
                                     const float* __restrict__ a_src, const float* __restrict__ a_dst,
                                     const float* __restrict__ msum, const float* __restrict__ q,
                                     int* __restrict__ csr_src, float* __restrict__ alphacsr) {
  const int k = blockIdx.x * blockDim.x + threadIdx.x;
  if (k >= TOT_E) return;
  int s, d, pos;
  float e0, e1, e2, e3;
  if (k < N_EDGES) {
    s = EI[k]; d = EI[N_EDGES + k];
    const float4 e = *(const float4*)&EA[(size_t)k * 4];
    e0 = e.x; e1 = e.y; e2 = e.z; e3 = e.w;
    pos = rowstart[d] + atomicAdd(&cnt[d], 1);
    csr_src[pos] = s;
  } else {
    s = d = k - N_EDGES;
    const float inv = 1.0f / (float)N_EDGES;
    e0 = msum[0] * inv; e1 = msum[1] * inv; e2 = msum[2] * inv; e3 = msum[3] * inv;
    pos = k;                       // self region: identity
  }
  const float4 as = *(const float4*)&a_src[s * 4];
  const float4 ad = *(const float4*)&a_dst[d * 4];
  const float asv[4] = {as.x, as.y, as.z, as.w};
  const float adv[4] = {ad.x, ad.y, ad.z, ad.w};
  float al[4];
#pragma unroll
  for (int h = 0; h < 4; ++h) {
    float ae = e0 * q[h] + e1 * q[4 + h] + e2 * q[8 + h] + e3 * q[12 + h];
    float a = asv[h] + adv[h] + ae;
    al[h] = (a >= 0.f) ? a : NEG_SLOPE * a;
  }
  float4 o = {al[0], al[1], al[2], al[3]};
  *(float4*)&alphacsr[(size_t)pos * 4] = o;
}

// ---- fused softmax + CSR gather-aggregate, bf16 out (R6 structure) ----
// One WAVE per node; lane l: channels l*8..l*8+7 (16B loads); head = l>>4.
__global__ __launch_bounds__(256) void agg_fused_kernel(
    const int* __restrict__ rowstart, const int* __restrict__ csr_src,
    const float* __restrict__ alphacsr, const unsigned short* __restrict__ H16,
    unsigned short* __restrict__ o16) {
  const int wid = threadIdx.x >> 6;
  const int n = blockIdx.x * 4 + wid;           // grid 5000 * 4 waves = 20000
  const int l = threadIdx.x & 63;
  const int head = l >> 4;
  const int j = l * 8;
  const int lo = l & 15;                        // lane within head group
  const int beg = rowstart[n], end = rowstart[n + 1];
  const float aself = alphacsr[(size_t)(N_EDGES + n) * 4 + head];
  // pass 1: per-head max (16-lane strided walk + butterfly)
  float m = aself;
  for (int p = beg + lo; p < end; p += 16)
    m = fmaxf(m, alphacsr[(size_t)p * 4 + head]);
#pragma unroll
  for (int mask = 1; mask <= 8; mask <<= 1) m = fmaxf(m, __shfl_xor(m, mask));
  // pass 2: denominator
  float den = 0.f;
  for (int p = beg + lo; p < end; p += 16)
    den += __expf(alphacsr[(size_t)p * 4 + head] - m);
#pragma unroll
  for (int mask = 1; mask <= 8; mask <<= 1) den += __shfl_xor(den, mask);
  den += __expf(aself - m);
  const float dinv = 1.0f / (den + 1e-16f);
  // pass 3: weighted gather, 1-ahead index prefetch
  const float wself = __expf(aself - m) * dinv;
  const u16x8 hv = *(const u16x8*)&H16[(size_t)n * HC + j];
  float acc[8];
#pragma unroll
  for (int c = 0; c < 8; ++c) acc[c] = wself * bf2f(hv[c]);
  int s_nxt = 0;
  if (beg < end) s_nxt = csr_src[beg];
  for (int idx = beg; idx < end; ++idx) {
    const int s = s_nxt;
    if (idx + 1 < end) s_nxt = csr_src[idx + 1];
    const float w = __expf(alphacsr[(size_t)idx * 4 + head] - m) * dinv;
    const u16x8 v = *(const u16x8*)&H16[(size_t)s * HC + j];
#pragma unroll
    for (int c = 0; c < 8; ++c) acc[c] += w * bf2f(v[c]);
  }
  unsigned short ov[8];
#pragma unroll
  for (int c = 0; c < 8; ++c) ov[c] = f2bf(acc[c]);
  *(short8v*)&o16[(size_t)n * HC + j] = *(short8v*)ov;
}

// ---- BN column sums / sums of squares from bf16 pre-BN output ----
__global__ void bn_stats16_kernel(const unsigned short* __restrict__ o16,
                                  float* __restrict__ psum, float* __restrict__ psq) {
  const int t = threadIdx.x;          // 256 threads -> 2 channels each
  const int j = t * 2;
  float s0 = 0.f, s1 = 0.f, q0 = 0.f, q1 = 0.f;
  for (int r = blockIdx.x; r < N_NODES; r += gridDim.x) {
    const unsigned v = *(const unsigned*)&o16[(size_t)r * HC + j];
    const float a = bf2f((unsigned short)(v & 0xffffu));
    const float b = bf2f((unsigned short)(v >> 16));
    s0 += a; s1 += b; q0 += a * a; q1 += b * b;
  }
  atomicAdd(&psum[j], s0);
  atomicAdd(&psum[j + 1], s1);
  atomicAdd(&psq[j], q0);
  atomicAdd(&psq[j + 1], q1);
}

// ---- BN normalize: scale/shift computed inline (bias cancels exactly) ----
__global__ void bn_apply_kernel(const unsigned short* __restrict__ o16,
                                const float* __restrict__ psum, const float* __restrict__ psq,
                                const float* __restrict__ gamma, const float* __restrict__ beta,
                                float* __restrict__ out) {
  const int i = blockIdx.x * blockDim.x + threadIdx.x;   // float4 index
  if (i >= N_NODES * HC / 4) return;
  const int j4 = (i & (HC / 4 - 1)) * 4;
  const float4 cs = *(const float4*)&psum[j4];
  const float4 cq = *(const float4*)&psq[j4];
  const float4 g  = *(const float4*)&gamma[j4];
  const float4 b  = *(const float4*)&beta[j4];
  const float inv = 1.0f / N_NODES;
  const float mux = cs.x * inv, muy = cs.y * inv, muz = cs.z * inv, muw = cs.w * inv;
  const float scx = g.x * rsqrtf(cq.x * inv - mux * mux + BN_EPS);
  const float scy = g.y * rsqrtf(cq.y * inv - muy * muy + BN_EPS);
  const float scz = g.z * rsqrtf(cq.z * inv - muz * muz + BN_EPS);
  const float scw = g.w * rsqrtf(cq.w * inv - muw * muw + BN_EPS);
  const u16x4 v16 = *(const u16x4*)&o16[(size_t)i * 4];
  float4 v;
  v.x = (bf2f(v16[0]) - mux) * scx + b.x;
  v.y = (bf2f(v16[1]) - muy) * scy + b.y;
  v.z = (bf2f(v16[2]) - muz) * scz + b.z;
  v.w = (bf2f(v16[3]) - muw) * scw + b.w;
  ((float4*)out)[i] = v;
}

extern "C" void kernel_launch(void* const* d_in, const int* in_sizes, int n_in,
                              void* d_out, int out_size, void* d_ws, size_t ws_size,
                              hipStream_t stream) {
  const float* x     = (const float*)d_in[0];
  const int*   ei    = (const int*)d_in[1];
  const float* ea    = (const float*)d_in[2];
  const float* W     = (const float*)d_in[3];
  const float* We    = (const float*)d_in[4];
  const float* att_s = (const float*)d_in[5];
  const float* att_d = (const float*)d_in[6];
  const float* att_e = (const float*)d_in[7];
  // d_in[8] = bias: cancels exactly in BatchNorm -> unused
  const float* gamma = (const float*)d_in[9];
  const float* beta  = (const float*)d_in[10];
  float* out = (float*)d_out;
  float* ws  = (float*)d_ws;

  // workspace layout
  unsigned short* H16     = (unsigned short*)ws;                   // N*512 bf16
  float*    a_src   = (float*)(H16 + (size_t)N_NODES * HC);        // N*4
  float*    a_dst   = a_src + N_NODES * NHEAD;                     // N*4
  float*    alphacsr= a_dst + N_NODES * NHEAD;                     // TOT_E*4
  float*    qm      = alphacsr + (size_t)TOT_E * NHEAD;            // 16
  int*      rowstart= (int*)(qm + 16);                             // N+1 (pad 20004)
  int*      csr_src = rowstart + 20004;                            // E
  unsigned short* Bp  = (unsigned short*)(csr_src + N_EDGES);      // 32*16*64*8 ush
  unsigned short* o16 = Bp + (size_t)32 * 16 * 64 * 8;             // N*512 bf16
  // ---- zeroed-every-call block ----
  int*      deg     = (int*)(o16 + (size_t)N_NODES * HC);          // N
  int*      cnt     = deg + N_NODES;                               // N
  float*    msum    = (float*)(cnt + N_NODES);                     // 4
  float*    psum    = msum + 4;                                    // 512
  float*    psq     = psum + HC;                                   // 512

  const size_t zero_bytes = (size_t)(N_NODES * 2 + 4 + HC * 2) * sizeof(float);
  hipMemsetAsync(deg, 0, zero_bytes, stream);

  prep_pack_kernel<<<PACK_BLOCKS + PREP_BLOCKS, 256, 0, stream>>>(
      W, Bp, ea, ei, We, att_e, msum, deg, qm);
  scan_kernel<<<1, 1024, 0, stream>>>(deg, rowstart);
  gemm_direct_fused<<<N_NODES / GEMM_BM, 256, 0, stream>>>(x, Bp, att_s, att_d,
                                                           H16, a_src, a_dst);
  scatter_alpha_kernel<<<(TOT_E + 255) / 256, 256, 0, stream>>>(ei, ea, rowstart, cnt,
                                                                a_src, a_dst, msum, qm,
                                                                csr_src, alphacsr);
  agg_fused_kernel<<<N_NODES / 4, 256, 0, stream>>>(rowstart, csr_src, alphacsr, H16, o16);
  bn_stats16_kernel<<<256, 256, 0, stream>>>(o16, psum, psq);
  bn_apply_kernel<<<(N_NODES * HC / 4 + 255) / 256, 256, 0, stream>>>(o16, psum, psq,
                                                                      gamma, beta, out);
}